// Round 15
// baseline (4917.537 us; speedup 1.0000x reference)
//
#include <hip/hip_runtime.h>
#include <hip/hip_bf16.h>
#include <hip/hip_fp16.h>
#include <math.h>

// Problem constants
#define BB 2
#define NN 1024
#define HID 2048
#define NH 16
#define KVH 4
#define DD 128
#define L_TOTAL 32768   // B*H*N flattened scan length
#define TOK 2048        // B*N tokens
#define NCHUNK 512      // 64-token chunks over the flattened sequence

// R18: padded LDS strides (bank-conflict fix without XOR address math)
#define STP 136   // ST row stride (was 128); byte stride 272 -> jloc*68 mod 32 spreads
#define UTP 72    // uT row stride (was 64);  byte stride 144 -> jloc*36 mod 32 spreads
#define XBP 17    // xb row stride (was 16);  row*17 mod 32 spreads the RMW

typedef __bf16 bf16;
typedef __bf16 bf16x8 __attribute__((ext_vector_type(8)));
typedef __bf16 bf16x4 __attribute__((ext_vector_type(4)));
typedef __bf16 bf16x2 __attribute__((ext_vector_type(2)));
typedef float f32x4 __attribute__((ext_vector_type(4)));

// ---------------------------------------------------------------------------
// Register-blocked MFMA GEMM (R13): C[m,n] = sum_k A[m,k] * BT[n,k].
// 64x64 per wave (4x4 fragments), 128x128 per block. Per-output arithmetic
// bit-identical to the R1-verified gemm_bt.
// Grid.x = (M/128)*(N/128). Requires M%128==0, N%128==0, K%32==0.
// ---------------------------------------------------------------------------
template<bool SPLIT, bool OUTBF>
__global__ __launch_bounds__(256)
void gemm64_bt(const bf16* __restrict__ A, const bf16* __restrict__ Alo,
               const bf16* __restrict__ B, const bf16* __restrict__ Blo,
               float* __restrict__ Cf, bf16* __restrict__ Cb,
               int M, int N, int K, int lda, int ldb, int ldc,
               long aSb, long aSh, long aSz, long bSb, long bSh, long cSz,
               int zH, int gShift, int z0)
{
    const int zc   = blockIdx.z;
    const int z    = zc + z0;
    const int b    = z / zH;
    const int h    = z % zH;
    const int lane = threadIdx.x & 63;
    const int wave = threadIdx.x >> 6;
    const int tiles_n = N >> 7;
    const int btm = blockIdx.x / tiles_n;
    const int btn = blockIdx.x % tiles_n;
    const int wr = wave >> 1, wc = wave & 1;
    const int r0 = btm * 128 + wr * 64;
    const int c0 = btn * 128 + wc * 64;
    const int l15 = lane & 15, kq = lane >> 4;

    const long aoff = (long)b * aSb + (long)h * aSh + (long)zc * aSz;
    const long boff = (long)b * bSb + (long)(h >> gShift) * bSh;

    const bf16* ap[4];
    const bf16* bp[4];
    #pragma unroll
    for (int m = 0; m < 4; ++m)
        ap[m] = A + aoff + (long)(r0 + m * 16 + l15) * lda + kq * 8;
    #pragma unroll
    for (int n = 0; n < 4; ++n)
        bp[n] = B + boff + (long)(c0 + n * 16 + l15) * ldb + kq * 8;

    f32x4 acc[4][4];
    #pragma unroll
    for (int m = 0; m < 4; ++m)
        #pragma unroll
        for (int n = 0; n < 4; ++n)
            acc[m][n] = (f32x4){0.f, 0.f, 0.f, 0.f};

    for (int k0 = 0; k0 < K; k0 += 32) {
        bf16x8 ah[4], bh[4], al[4], bl[4];
        #pragma unroll
        for (int m = 0; m < 4; ++m) {
            ah[m] = *(const bf16x8*)ap[m];
            if (SPLIT) al[m] = *(const bf16x8*)(Alo + (ap[m] - A));
        }
        #pragma unroll
        for (int n = 0; n < 4; ++n) {
            bh[n] = *(const bf16x8*)bp[n];
            if (SPLIT) bl[n] = *(const bf16x8*)(Blo + (bp[n] - B));
        }
        #pragma unroll
        for (int m = 0; m < 4; ++m)
            #pragma unroll
            for (int n = 0; n < 4; ++n) {
                acc[m][n] = __builtin_amdgcn_mfma_f32_16x16x32_bf16(ah[m], bh[n], acc[m][n], 0, 0, 0);
                if (SPLIT) {
                    acc[m][n] = __builtin_amdgcn_mfma_f32_16x16x32_bf16(al[m], bh[n], acc[m][n], 0, 0, 0);
                    acc[m][n] = __builtin_amdgcn_mfma_f32_16x16x32_bf16(ah[m], bl[n], acc[m][n], 0, 0, 0);
                }
            }
        #pragma unroll
        for (int m = 0; m < 4; ++m) ap[m] += 32;
        #pragma unroll
        for (int n = 0; n < 4; ++n) bp[n] += 32;
    }

    // epilogue: C/D mapping as gemm_bt (col = lane&15, row = kq*4 + r)
    #pragma unroll
    for (int m = 0; m < 4; ++m)
        #pragma unroll
        for (int n = 0; n < 4; ++n) {
            const long cbase = (long)zc * cSz + (long)(c0 + n * 16 + l15);
            const int  rr0   = r0 + m * 16 + kq * 4;
            #pragma unroll
            for (int r = 0; r < 4; ++r) {
                long idx = cbase + (long)(rr0 + r) * ldc;
                if (OUTBF) Cb[idx] = (bf16)acc[m][n][r];
                else       Cf[idx] = acc[m][n][r];
            }
        }
}

// ---------------------------------------------------------------------------
// Elementwise helpers
// ---------------------------------------------------------------------------
__global__ void cast_split_k(const float* __restrict__ in, bf16* __restrict__ hi,
                             bf16* __restrict__ lo, long n)
{
    long i = (long)blockIdx.x * blockDim.x + threadIdx.x;
    if (i < n) {
        float x = in[i];
        bf16 h = (bf16)x;
        hi[i] = h;
        lo[i] = (bf16)(x - (float)h);
    }
}

__global__ void transpose_split_k(const float* __restrict__ in, bf16* __restrict__ hi,
                                  bf16* __restrict__ lo, int K, int N)
{
    long i = (long)blockIdx.x * blockDim.x + threadIdx.x;
    if (i < (long)K * N) {
        int n = (int)(i / K);
        int k = (int)(i % K);
        float x = in[(long)k * N + n];
        bf16 h = (bf16)x;
        hi[i] = h;
        lo[i] = (bf16)(x - (float)h);
    }
}

// Merged vtrans + ktrans + vbpack (identical index domain, one launch).
__global__ void prep_pack_k(const float* __restrict__ vf, const float* __restrict__ KLb,
                            const float* __restrict__ GLb,
                            bf16* __restrict__ vT, bf16* __restrict__ KThi,
                            bf16* __restrict__ KTlo, float* __restrict__ Vp,
                            float* __restrict__ Bp)
{
    long i = (long)blockIdx.x * blockDim.x + threadIdx.x;
    if (i < 1048576) {
        // vtrans: vT[b][kvh][m][d] = vf[(b*1024+m)*512 + kvh*128 + d]
        {
            int m   = (int)(i & 1023);
            int d   = (int)((i >> 10) & 127);
            int kvh = (int)((i >> 17) & 3);
            int b   = (int)(i >> 19);
            vT[i] = (bf16)vf[((long)(b * 1024 + m)) * 512 + kvh * 128 + d];
        }
        // ktrans: KT[a][d][t] = split(KLb[(b*1024+nc*64+t)*512 + kvh*128 + d])
        {
            int t = (int)(i & 63);
            int d = (int)((i >> 6) & 127);
            int a = (int)(i >> 13);
            int b = a >> 6, kvh = (a >> 4) & 3, nc = a & 15;
            float x = KLb[((long)(b * 1024 + nc * 64 + t)) * 512 + kvh * 128 + d];
            bf16 h = (bf16)x;
            KThi[i] = h;
            KTlo[i] = (bf16)(x - (float)h);
        }
        // vbpack: Vp/Bp[a][j][s]
        {
            int s = (int)(i & 63);
            int j = (int)((i >> 6) & 127);
            int a = (int)(i >> 13);
            int b = a >> 6, kvh = (a >> 4) & 3, nc = a & 15;
            long src = ((long)(b * 1024 + nc * 64 + s)) * 512 + kvh * 128 + j;
            Vp[i] = vf[src];
            Bp[i] = GLb[src];
        }
    }
}

// R14 fused q-prep.
__global__ void softmaxq_fused_k(const float* __restrict__ in,
                                 bf16* __restrict__ hi, bf16* __restrict__ lo,
                                 bf16* __restrict__ rawb)
{
    const int row  = blockIdx.x;
    const int lane = threadIdx.x;
    float2 v = ((const float2*)(in + (long)row * 128))[lane];
    ((bf16x2*)(rawb + (long)row * 128))[lane] = (bf16x2){(bf16)v.x, (bf16)v.y};
    float m = fmaxf(v.x, v.y);
    #pragma unroll
    for (int s = 1; s < 64; s <<= 1) m = fmaxf(m, __shfl_xor(m, s, 64));
    float ex = expf(v.x - m), ey = expf(v.y - m);
    float sum = ex + ey;
    #pragma unroll
    for (int s = 1; s < 64; s <<= 1) sum += __shfl_xor(sum, s, 64);
    float inv = 1.0f / sum;
    float x0 = ex * inv, x1 = ey * inv;
    bf16 h0 = (bf16)x0, h1 = (bf16)x1;
    ((bf16x2*)(hi + (long)row * 128))[lane] = (bf16x2){h0, h1};
    ((bf16x2*)(lo + (long)row * 128))[lane] =
        (bf16x2){(bf16)(x0 - (float)h0), (bf16)(x1 - (float)h1)};
}

// R14 fused k-prep.
__global__ void softmaxk_fused_k(const float* __restrict__ in,
                                 float* __restrict__ KLb,
                                 bf16* __restrict__ hi, bf16* __restrict__ lo,
                                 bf16* __restrict__ rawb, float* __restrict__ GLb)
{
    const int row  = blockIdx.x;
    const int lane = threadIdx.x;
    float2 v = ((const float2*)(in + (long)row * 128))[lane];
    ((bf16x2*)(rawb + (long)row * 128))[lane] = (bf16x2){(bf16)v.x, (bf16)v.y};
    float g0 = (fminf(v.x, 0.f) - log1pf(expf(-fabsf(v.x)))) * 0.0625f;
    float g1 = (fminf(v.y, 0.f) - log1pf(expf(-fabsf(v.y)))) * 0.0625f;
    ((float2*)(GLb + (long)row * 128))[lane] = make_float2(g0, g1);
    float m = fmaxf(v.x, v.y);
    #pragma unroll
    for (int s = 1; s < 64; s <<= 1) m = fmaxf(m, __shfl_xor(m, s, 64));
    float ex = expf(v.x - m), ey = expf(v.y - m);
    float sum = ex + ey;
    #pragma unroll
    for (int s = 1; s < 64; s <<= 1) sum += __shfl_xor(sum, s, 64);
    float inv = 1.0f / sum;
    float x0 = ex * inv, x1 = ey * inv;
    ((float2*)(KLb + (long)row * 128))[lane] = make_float2(x0, x1);
    bf16 h0 = (bf16)x0, h1 = (bf16)x1;
    ((bf16x2*)(hi + (long)row * 128))[lane] = (bf16x2){h0, h1};
    ((bf16x2*)(lo + (long)row * 128))[lane] =
        (bf16x2){(bf16)(x0 - (float)h0), (bf16)(x1 - (float)h1)};
}

__global__ void softmax_causal_k(bf16* __restrict__ P)
{
    const int row  = blockIdx.x;
    const int qi   = row & 1023;
    const int lane = threadIdx.x;
    bf16* p = P + (long)row * 1024;
    const float scale = 0.08838834764831845f;  // 1/sqrt(128)
    float vals[16];
    float m = -3.0e38f;
    #pragma unroll
    for (int t = 0; t < 16; ++t) {
        int j = lane + t * 64;
        float x = (j <= qi) ? (float)p[j] * scale : -3.0e38f;
        vals[t] = x;
        m = fmaxf(m, x);
    }
    #pragma unroll
    for (int s = 1; s < 64; s <<= 1) m = fmaxf(m, __shfl_xor(m, s, 64));
    float sum = 0.f;
    #pragma unroll
    for (int t = 0; t < 16; ++t) {
        float e = (vals[t] > -1.0e38f) ? expf(vals[t] - m) : 0.f;
        vals[t] = e;
        sum += e;
    }
    #pragma unroll
    for (int s = 1; s < 64; s <<= 1) sum += __shfl_xor(sum, s, 64);
    float inv = 1.f / sum;
    #pragma unroll
    for (int t = 0; t < 16; ++t) {
        int j = lane + t * 64;
        p[j] = (bf16)(vals[t] * inv);
    }
}

// A = tril_strict(K Kt) per kv-chunk (128) — MFMA version (R12).
__global__ __launch_bounds__(256)
void prepA_mfma_k(const bf16* __restrict__ KLhi, const bf16* __restrict__ KLlo,
                  bf16* __restrict__ Abhi, bf16* __restrict__ Ablo,
                  float* __restrict__ ATf)
{
    const int a = blockIdx.x;
    const int b = a >> 6, kvh = (a >> 4) & 3, nc = a & 15;
    const long rbase = ((long)(b * 1024 + nc * 64)) * 512 + kvh * 128;
    const int wave = threadIdx.x >> 6, lane = threadIdx.x & 63;
    const int l15 = lane & 15, kq = lane >> 4;

    #pragma unroll
    for (int it = 0; it < 4; ++it) {
        const int tile = wave * 4 + it;
        const int mt = tile >> 2, nt = tile & 3;    // mt: t-tile (rows), nt: s-tile (cols)
        f32x4 acc = {0.f, 0.f, 0.f, 0.f};
        if (nt <= mt) {                              // tiles above diagonal are all-zero
            const long arow = rbase + (long)(mt * 16 + l15) * 512 + kq * 8;
            const long brow = rbase + (long)(nt * 16 + l15) * 512 + kq * 8;
            #pragma unroll
            for (int ki = 0; ki < 4; ++ki) {
                bf16x8 ah = *(const bf16x8*)(KLhi + arow + ki * 32);
                bf16x8 al = *(const bf16x8*)(KLlo + arow + ki * 32);
                bf16x8 bh = *(const bf16x8*)(KLhi + brow + ki * 32);
                bf16x8 bl = *(const bf16x8*)(KLlo + brow + ki * 32);
                acc = __builtin_amdgcn_mfma_f32_16x16x32_bf16(ah, bh, acc, 0, 0, 0);
                acc = __builtin_amdgcn_mfma_f32_16x16x32_bf16(al, bh, acc, 0, 0, 0);
                acc = __builtin_amdgcn_mfma_f32_16x16x32_bf16(ah, bl, acc, 0, 0, 0);
            }
        }
        const int s  = nt * 16 + l15;                // C/D col = lane&15
        const int r0 = mt * 16 + kq * 4;             // C/D row = kq*4 + r
        #pragma unroll
        for (int r = 0; r < 4; ++r) {
            int t = r0 + r;
            float dot = (s < t) ? acc[r] : 0.f;
            bf16 hh = (bf16)dot;
            Abhi[(long)a * 4096 + t * 64 + s] = hh;
            Ablo[(long)a * 4096 + t * 64 + s] = (bf16)(dot - (float)hh);
            ATf[(long)a * 4096 + s * 64 + t] = dot;
        }
    }
}

// Aq = tril_inclusive(Q Kt) per chunk (512) — MFMA version (R12).
__global__ __launch_bounds__(256)
void prepAq_mfma_k(const bf16* __restrict__ QLhi, const bf16* __restrict__ QLlo,
                   const bf16* __restrict__ KLhi, const bf16* __restrict__ KLlo,
                   bf16* __restrict__ Aqhi, bf16* __restrict__ Aqlo)
{
    const int c = blockIdx.x;
    const int b = c >> 8, h = (c >> 4) & 15, nc = c & 15, kvh = h >> 2;
    const long qb = ((long)(b * 1024 + nc * 64)) * 2048 + h * 128;
    const long kb = ((long)(b * 1024 + nc * 64)) * 512 + kvh * 128;
    const int wave = threadIdx.x >> 6, lane = threadIdx.x & 63;
    const int l15 = lane & 15, kq = lane >> 4;

    #pragma unroll
    for (int it = 0; it < 4; ++it) {
        const int tile = wave * 4 + it;
        const int mt = tile >> 2, nt = tile & 3;
        f32x4 acc = {0.f, 0.f, 0.f, 0.f};
        if (nt <= mt) {                              // strict-upper tiles all-zero
            const long arow = qb + (long)(mt * 16 + l15) * 2048 + kq * 8;
            const long brow = kb + (long)(nt * 16 + l15) * 512 + kq * 8;
            #pragma unroll
            for (int ki = 0; ki < 4; ++ki) {
                bf16x8 ah = *(const bf16x8*)(QLhi + arow + ki * 32);
                bf16x8 al = *(const bf16x8*)(QLlo + arow + ki * 32);
                bf16x8 bh = *(const bf16x8*)(KLhi + brow + ki * 32);
                bf16x8 bl = *(const bf16x8*)(KLlo + brow + ki * 32);
                acc = __builtin_amdgcn_mfma_f32_16x16x32_bf16(ah, bh, acc, 0, 0, 0);
                acc = __builtin_amdgcn_mfma_f32_16x16x32_bf16(al, bh, acc, 0, 0, 0);
                acc = __builtin_amdgcn_mfma_f32_16x16x32_bf16(ah, bl, acc, 0, 0, 0);
            }
        }
        const int s  = nt * 16 + l15;
        const int r0 = mt * 16 + kq * 4;
        #pragma unroll
        for (int r = 0; r < 4; ++r) {
            int t = r0 + r;
            float dot = (s <= t) ? acc[r] : 0.f;
            bf16 hh = (bf16)dot;
            Aqhi[(long)c * 4096 + t * 64 + s] = hh;
            Aqlo[(long)c * 4096 + t * 64 + s] = (bf16)(dot - (float)hh);
        }
    }
}

// ---------------------------------------------------------------------------
// Sequential chunked delta-rule scan (R15 structure).
// R18 (single change): LDS layouts padded — ST row stride 128->136, uT
// 64->72, xb 16->17 — removing the 16-way ds conflicts on ST reads and the
// per-step uT scalar stores, and the 4-way xb write conflicts, with zero
// added address math (pad constant folds into the existing multiply).
// Copy-out re-derived for the padded uT layout (global side bit-identical).
// ---------------------------------------------------------------------------
__global__ __launch_bounds__(64, 1)
void seq_scan_k(const bf16* __restrict__ KLhi, const bf16* __restrict__ KLlo,
                const bf16* __restrict__ KThi, const bf16* __restrict__ KTlo,
                const bf16* __restrict__ Abhi, const bf16* __restrict__ Ablo,
                const float* __restrict__ ATf, const float* __restrict__ Vp,
                const float* __restrict__ Bp,
                bf16* __restrict__ S0Thi, bf16* __restrict__ S0Tlo,
                bf16* __restrict__ uTghi, bf16* __restrict__ uTglo)
{
    __shared__ __align__(16) bf16  SThi[16 * STP];
    __shared__ __align__(16) bf16  STlo[16 * STP];
    __shared__ __align__(16) bf16  uThi[16 * UTP];
    __shared__ __align__(16) bf16  uTlo[16 * UTP];
    __shared__ __align__(16) float xb[64 * XBP];
    __shared__ __align__(16) float ATl[4096];

    const int lane  = threadIdx.x;
    const int jloc  = lane & 15;
    const int kq    = lane >> 4;          // quad 0..3
    const int jglob = blockIdx.x * 16 + jloc;

    // zero LDS state; zero S0T[0] slice for this block's columns
    for (int i = lane; i < 16 * STP; i += 64) { SThi[i] = (bf16)0.f; STlo[i] = (bf16)0.f; }
    for (int i = lane; i < 16 * 128; i += 64) {
        int j = i >> 7, d = i & 127;
        long off = (long)(blockIdx.x * 16 + j) * 128 + d;
        S0Thi[off] = (bf16)0.f;
        S0Tlo[off] = (bf16)0.f;
    }

    f32x4 S[8];
    #pragma unroll
    for (int m = 0; m < 8; ++m) S[m] = (f32x4){0.f, 0.f, 0.f, 0.f};

    for (int c = 0; c < NCHUNK; ++c) {
        const int b = c >> 8, h = (c >> 4) & 15, nc = c & 15;
        const int kvh = h >> 2, n0 = nc * 64;
        const long krow0  = ((long)(b * 1024 + n0)) * 512 + kvh * 128;   // KL rows, stride 512
        const int  achunk = (b * 4 + kvh) * 16 + nc;
        const long abase  = (long)achunk * 4096;
        const long ktbase = (long)achunk * 8192;                         // KT [d][t]
        const float* vpb  = Vp + ((long)achunk * 128 + jglob) * 64;
        const float* bpb  = Bp + ((long)achunk * 128 + jglob) * 64;

        // ---- KL fragments for this chunk (issued first: W consumes first)
        bf16x8 klh[16], kll[16];
        #pragma unroll
        for (int m = 0; m < 4; ++m)
            #pragma unroll
            for (int ki = 0; ki < 4; ++ki) {
                long ko = krow0 + (long)(m * 16 + jloc) * 512 + ki * 32 + kq * 8;
                klh[m * 4 + ki] = *(const bf16x8*)(KLhi + ko);
                kll[m * 4 + ki] = *(const bf16x8*)(KLlo + ko);
            }

        // ---- issue AT panel loads (regs); latency hides under W ----
        float4 atReg[16];
        {
            const float* src = ATf + abase;
            #pragma unroll
            for (int u = 0; u < 16; ++u)
                atReg[u] = *(const float4*)(src + u * 256 + lane * 4);
        }

        // ---- Ab correction fragments hoisted to chunk top (read-only) ----
        bf16x8 abh[4], abl[4];
        #pragma unroll
        for (int q = 0; q < 4; ++q) {
            const int tt = (q < 2) ? (16 + q * 16) : 48;   // 16,32,48,48
            const int kk = (q == 3) ? 1 : 0;
            long ao = abase + (long)(tt + jloc) * 64 + kk * 32 + kq * 8;
            abh[q] = *(const bf16x8*)(Abhi + ao);
            abl[q] = *(const bf16x8*)(Ablo + ao);
        }

        // ---- V/B for SB0 issued at chunk top (packed, float4) ----
        float Vv[2][16], Bv[2][16];
        #pragma unroll
        for (int g = 0; g < 4; ++g) {
            float4 v4 = *(const float4*)(vpb + g * 4);
            Vv[0][g * 4 + 0] = v4.x; Vv[0][g * 4 + 1] = v4.y;
            Vv[0][g * 4 + 2] = v4.z; Vv[0][g * 4 + 3] = v4.w;
            float4 b4 = *(const float4*)(bpb + g * 4);
            Bv[0][g * 4 + 0] = b4.x; Bv[0][g * 4 + 1] = b4.y;
            Bv[0][g * 4 + 2] = b4.z; Bv[0][g * 4 + 3] = b4.w;
        }

        // ---- W = K * S0 (3-MFMA split), KL from chunk-top registers ----
        f32x4 W[4];
        #pragma unroll
        for (int m = 0; m < 4; ++m) W[m] = (f32x4){0.f, 0.f, 0.f, 0.f};
        #pragma unroll
        for (int ki = 0; ki < 4; ++ki) {
            bf16x8 sh = *(const bf16x8*)&SThi[jloc * STP + ki * 32 + kq * 8];
            bf16x8 sl = *(const bf16x8*)&STlo[jloc * STP + ki * 32 + kq * 8];
            #pragma unroll
            for (int m = 0; m < 4; ++m) {
                W[m] = __builtin_amdgcn_mfma_f32_16x16x32_bf16(klh[m * 4 + ki], sh, W[m], 0, 0, 0);
                W[m] = __builtin_amdgcn_mfma_f32_16x16x32_bf16(kll[m * 4 + ki], sh, W[m], 0, 0, 0);
                W[m] = __builtin_amdgcn_mfma_f32_16x16x32_bf16(klh[m * 4 + ki], sl, W[m], 0, 0, 0);
            }
        }
        // epilogue: x[t][j] = W   (C/D: col=lane&15=j, row=kq*4+r)
        #pragma unroll
        for (int m = 0; m < 4; ++m)
            #pragma unroll
            for (int r = 0; r < 4; ++r)
                xb[(m * 16 + kq * 4 + r) * XBP + jloc] = W[m][r];

        // ---- commit AT panel to LDS (loads have retired by W's end) ----
        #pragma unroll
        for (int u = 0; u < 16; ++u)
            *(float4*)(ATl + u * 256 + lane * 4) = atReg[u];

        // ---- KT fragments issued here; latency hides under the SB loop ----
        bf16x8 kth[16], ktl[16];
        #pragma unroll
        for (int m = 0; m < 8; ++m)
            #pragma unroll
            for (int ki = 0; ki < 2; ++ki) {
                long o = ktbase + (long)(m * 16 + jloc) * 64 + ki * 32 + kq * 8;
                kth[m * 2 + ki] = *(const bf16x8*)(KThi + o);
                ktl[m * 2 + ki] = *(const bf16x8*)(KTlo + o);
            }

        // zero u buffers (cols 0..15 rewritten in SB0 before any read);
        // 16*UTP bf16 = 16*72*2/16 = 144 uint4 per buffer
        {
            uint4 z = {0u, 0u, 0u, 0u};
            for (int i = lane; i < 144; i += 64) {
                ((uint4*)uThi)[i] = z;
                ((uint4*)uTlo)[i] = z;
            }
        }

        // ---- 4 sub-blocks of 16 ----
        #pragma unroll
        for (int i = 0; i < 4; ++i) {
            const int T0 = i * 16;
            if (i > 0) {
                // cross-SB correction: corr[j][t] = sum_{s<16i} u[j][s]*A[t][s]
                const int K32 = (i + 1) >> 1;   // 1,1,2
                const int fb  = i - 1;          // hoisted-frag base
                f32x4 corr = (f32x4){0.f, 0.f, 0.f, 0.f};
                #pragma unroll
                for (int ki = 0; ki < 2; ++ki) if (ki < K32) {
                    bf16x8 uh = *(const bf16x8*)&uThi[jloc * UTP + ki * 32 + kq * 8];
                    bf16x8 ul = *(const bf16x8*)&uTlo[jloc * UTP + ki * 32 + kq * 8];
                    corr = __builtin_amdgcn_mfma_f32_16x16x32_bf16(uh, abh[fb + ki], corr, 0, 0, 0);
                    corr = __builtin_amdgcn_mfma_f32_16x16x32_bf16(ul, abh[fb + ki], corr, 0, 0, 0);
                    corr = __builtin_amdgcn_mfma_f32_16x16x32_bf16(uh, abl[fb + ki], corr, 0, 0, 0);
                }
                // D[m=j][n=t]: col=lane&15 -> t=T0+jloc ; rows j = kq*4+r. RMW into x.
                #pragma unroll
                for (int r = 0; r < 4; ++r)
                    xb[(T0 + jloc) * XBP + kq * 4 + r] += corr[r];
            }

            // Xv preload: take the per-step ds_read off the serial chain
            float Xv[16];
            #pragma unroll
            for (int s = 0; s < 16; ++s) Xv[s] = xb[(T0 + s) * XBP + jloc];

            // V/B prefetch for the NEXT sub-block (packed, float4)
            if (i < 3) {
                #pragma unroll
                for (int g = 0; g < 4; ++g) {
                    float4 v4 = *(const float4*)(vpb + T0 + 16 + g * 4);
                    Vv[(i + 1) & 1][g * 4 + 0] = v4.x; Vv[(i + 1) & 1][g * 4 + 1] = v4.y;
                    Vv[(i + 1) & 1][g * 4 + 2] = v4.z; Vv[(i + 1) & 1][g * 4 + 3] = v4.w;
                    float4 b4 = *(const float4*)(bpb + T0 + 16 + g * 4);
                    Bv[(i + 1) & 1][g * 4 + 0] = b4.x; Bv[(i + 1) & 1][g * 4 + 1] = b4.y;
                    Bv[(i + 1) & 1][g * 4 + 2] = b4.z; Bv[(i + 1) & 1][g * 4 + 3] = b4.w;
                }
            }

            // AT row prefetch ring (depth 8) from LDS, rows pre-masked
            float rb[8][16];
            #pragma unroll
            for (int p = 0; p < 8; ++p) {
                const float* rp = ATl + (T0 + p) * 64 + T0;
                #pragma unroll
                for (int g = 0; g < 4; ++g) {
                    float4 v4 = *(const float4*)(rp + g * 4);
                    rb[p][g * 4 + 0] = v4.x; rb[p][g * 4 + 1] = v4.y;
                    rb[p][g * 4 + 2] = v4.z; rb[p][g * 4 + 3] = v4.w;
                }
            }

            float acc[16];
            #pragma unroll
            for (int t = 0; t < 16; ++t) acc[t] = 0.f;

            #pragma unroll
            for (int s = 0; s < 16; ++s) {
                float u = Bv[i & 1][s] * (Vv[i & 1][s] - Xv[s] - acc[s]);
                bf16 uh = (bf16)u;
                bf16 ul = (bf16)(u - (float)uh);
                if (lane < 16) {
                    uThi[jloc * UTP + T0 + s] = uh;
                    uTlo[jloc * UTP + T0 + s] = ul;
                }
                // acc[t] += AT[s][t]*u for t>s (pruned statically)
                #pragma unroll
                for (int t = 0; t < 16; ++t)
                    if (t > s) acc[t] += rb[s & 7][t] * u;
                // refill ring slot with row s+8 (clamped; unused slots harmless)
                {
                    int rr = T0 + s + 8; if (rr > 63) rr = 63;
                    const float* rp = ATl + rr * 64 + T0;
                    #pragma unroll
                    for (int g = 0; g < 4; ++g) {
                        float4 v4 = *(const float4*)(rp + g * 4);
                        rb[s & 7][g * 4 + 0] = v4.x; rb[s & 7][g * 4 + 1] = v4.y;
                        rb[s & 7][g * 4 + 2] = v4.z; rb[s & 7][g * 4 + 3] = v4.w;
                    }
                }
            }
        }

        // ---- S += Kt * u (3-term split) ----
        #pragma unroll
        for (int ki = 0; ki < 2; ++ki) {
            bf16x8 uh = *(const bf16x8*)&uThi[jloc * UTP + ki * 32 + kq * 8];
            bf16x8 ul = *(const bf16x8*)&uTlo[jloc * UTP + ki * 32 + kq * 8];
            #pragma unroll
            for (int m = 0; m < 8; ++m) {
                S[m] = __builtin_amdgcn_mfma_f32_16x16x32_bf16(kth[m * 2 + ki], uh, S[m], 0, 0, 0);
                S[m] = __builtin_amdgcn_mfma_f32_16x16x32_bf16(kth[m * 2 + ki], ul, S[m], 0, 0, 0);
                S[m] = __builtin_amdgcn_mfma_f32_16x16x32_bf16(ktl[m * 2 + ki], uh, S[m], 0, 0, 0);
            }
        }

        // ---- bulk u -> global (padded-LDS read side; global layout
        //      unchanged: row j at offset j*64, col g*8) ----
        {
            const int jr = lane >> 3, g = lane & 7;   // rows 0..7, 8-elem groups
            uint4 h0 = *(const uint4*)&uThi[jr * UTP + g * 8];
            uint4 h1 = *(const uint4*)&uThi[(jr + 8) * UTP + g * 8];
            uint4 l0 = *(const uint4*)&uTlo[jr * UTP + g * 8];
            uint4 l1 = *(const uint4*)&uTlo[(jr + 8) * UTP + g * 8];
            uint4* gh = (uint4*)(uTghi + ((long)c * 128 + blockIdx.x * 16) * 64);
            uint4* gl = (uint4*)(uTglo + ((long)c * 128 + blockIdx.x * 16) * 64);
            gh[lane] = h0; gh[lane + 64] = h1;
            gl[lane] = l0; gl[lane + 64] = l1;
        }

        // ---- S split epilogue: ST (LDS, padded) + S0T[c+1] (global) ----
        #pragma unroll
        for (int m = 0; m < 8; ++m) {
            bf16x4 h4, l4;
            #pragma unroll
            for (int r = 0; r < 4; ++r) {
                float v = S[m][r];
                bf16 hh = (bf16)v;
                h4[r] = hh;
                l4[r] = (bf16)(v - (float)hh);
            }
            int d0 = m * 16 + kq * 4;
            *(bf16x4*)&SThi[jloc * STP + d0] = h4;
            *(bf16x4*)&STlo[jloc * STP + d0] = l4;
            long goff = (long)(c + 1) * 16384 + (long)jglob * 128 + d0;
            *(bf16x4*)(S0Thi + goff) = h4;
            *(bf16x4*)(S0Tlo + goff) = l4;
        }
    }
}

// ---------------------------------------------------------------------------
// Pass 2 (fully parallel): o[t][j] = Q*S0_c + tril_incl(Aq)*u  per chunk.
// ---------------------------------------------------------------------------
__global__ __launch_bounds__(256)
void pass2_o_k(const bf16* __restrict__ QLhi, const bf16* __restrict__ QLlo,
               const bf16* __restrict__ S0Thi, const bf16* __restrict__ S0Tlo,
               const bf16* __restrict__ Aqhi, const bf16* __restrict__ Aqlo,
               const bf16* __restrict__ uTghi, const bf16* __restrict__ uTglo,
               float* __restrict__ O)
{
    const int c    = blockIdx.x >> 3;
    const int tg   = blockIdx.x & 7;
    const int wave = threadIdx.x >> 6;
    const int lane = threadIdx.x & 63;
    const int tt   = tg * 4 + wave;
    const int mt   = tt >> 3, nt = tt & 7;
    const int b = c >> 8, h = (c >> 4) & 15, nc = c & 15, n0 = nc * 64;
    const int kq = lane >> 4, l15 = lane & 15;

    const long qrow   = ((long)(b * 1024 + n0 + mt * 16 + l15)) * 2048 + h * 128;
    const long sbase  = (long)c * 16384 + (long)(nt * 16 + l15) * 128;
    const long aqbase = (long)c * 4096 + (long)(mt * 16 + l15) * 64;
    const long ubase  = ((long)(c * 128 + nt * 16 + l15)) * 64;

    f32x4 acc = {0.f, 0.f, 0.f, 0.f};
    #pragma unroll
    for (int ki = 0; ki < 4; ++ki) {
        bf16x8 qh = *(const bf16x8*)(QLhi + qrow + ki * 32 + kq * 8);
        bf16x8 ql = *(const bf16x8*)(QLlo + qrow + ki * 32 + kq * 8);
        bf16x8 sh = *(const bf16x8*)(S0Thi + sbase + ki * 32 + kq * 8);
        bf16x8 sl = *(const bf16x8*)(S0Tlo + sbase + ki * 32 + kq * 8);
        acc = __builtin_amdgcn_mfma_f32_16x16x32_bf16(qh, sh, acc, 0, 0, 0);
        acc = __builtin_amdgcn_mfma_f32_16x16x32_bf16(ql, sh, acc, 0, 0, 0);
        acc = __builtin_amdgcn_mfma_f32_16x16x32_bf16(qh, sl, acc, 0, 0, 0);
    }
    #pragma unroll
    for (int ki = 0; ki < 2; ++ki) {
        bf16x8 ah = *(const bf16x8*)(Aqhi + aqbase + ki * 32 + kq * 8);
        bf16x8 al = *(const bf16x8*)(Aqlo + aqbase + ki * 32 + kq * 8);
        bf16x8 uh = *(const bf16x8*)(uTghi + ubase + ki * 32 + kq * 8);
        bf16x8 ul = *(const bf16x8*)(uTglo + ubase + ki * 32 + kq * 8);
        acc = __builtin_amdgcn_mfma_f32_16x16x32_bf16(ah, uh, acc, 0, 0, 0);
        acc = __builtin_amdgcn_mfma_f32_16x16x32_bf16(al, uh, acc, 0, 0, 0);
        acc = __builtin_amdgcn_mfma_f32_16x16x32_bf16(ah, ul, acc, 0, 0, 0);
    }
    #pragma unroll
    for (int r = 0; r < 4; ++r)
        O[((long)c * 64 + mt * 16 + kq * 4 + r) * 128 + nt * 16 + l15] = acc[r];
}

// oComb[(b,n),(h,d)] = 0.5*(oLin[(b,h,n),d] + oBase[(b,h,n),d])  -> bf16
__global__ void combine_k(const float* __restrict__ oLin, const bf16* __restrict__ oBase,
                          bf16* __restrict__ oComb, long n)
{
    long i = (long)blockIdx.x * blockDim.x + threadIdx.x;
    if (i < n) {
        int d  = (int)(i & 127);
        int hh = (int)((i >> 7) & 15);
        int nn = (int)((i >> 11) & 1023);
        int b  = (int)(i >> 21);
        long src = ((long)((b * 16 + hh) * 1024 + nn)) * 128 + d;
        oComb[i] = (bf16)(0.5f * (oLin[src] + (float)oBase[src]));
    }
}

// ---------------------------------------------------------------------------
extern "C" void kernel_launch(void* const* d_in, const int* in_sizes, int n_in,
                              void* d_out, int out_size, void* d_ws, size_t ws_size,
                              hipStream_t stream)
{
    const float* hs = (const float*)d_in[0];
    const float* Wq = (const float*)d_in[1];
    const float* Wk = (const float*)d_in[2];
    const float* Wv = (const float*)d_in[3];
    const float* Wo = (const float*)d_in[4];

    char* base = (char*)d_ws;
    size_t off = 0;
    auto alloc = [&](size_t bytes) -> char* {
        char* r = base + off;
        off += (bytes + 255) & ~(size_t)255;
        return r;
    };

    bf16* hsHi  = (bf16*)alloc((long)TOK * 2048 * 2);
    bf16* hsLo  = (bf16*)alloc((long)TOK * 2048 * 2);
    bf16* WqTHi = (bf16*)alloc(2048L * 2048 * 2);
    bf16* WqTLo = (bf16*)alloc(2048L * 2048 * 2);
    bf16* WkTHi = (bf16*)alloc(512L * 2048 * 2);
    bf16* WkTLo = (bf16*)alloc(512L * 2048 * 2);
    bf16* WvTHi = (bf16*)alloc(512L * 2048 * 2);
    bf16* WvTLo = (bf16*)alloc(512L * 2048 * 2);
    bf16* WoTHi = (bf16*)alloc(2048L * 2048 * 2);
    bf16* WoTLo = (bf16*)alloc(2048L * 2048 * 2);
    float* qf   = (float*)alloc((long)TOK * 2048 * 4);
    float* kf   = (float*)alloc((long)TOK * 512 * 4);
    float* vf   = (float*)alloc((long)TOK * 512 * 4);
    float* KLb  = (float*)alloc((long)TOK * 512 * 4);
    float* GLb  = (float*)alloc((long)TOK * 512 * 4);
    float* Vp   = (float*)alloc(1048576L * 4);
    float* Bp   = (float*)alloc(1048576L * 4);
    bf16* qhB   = (bf16*)alloc((long)TOK * 2048 * 2);
    bf16* khB   = (bf16*)alloc((long)TOK * 512 * 2);
    bf16* vT    = (bf16*)alloc(1048576L * 2);
    bf16* P     = (bf16*)alloc(8L * 1024 * 1024 * 2);
    float* oLin = (float*)alloc(32768L * 128 * 4);
    bf16* oBase = (bf16*)alloc(32768L * 128 * 2);
    bf16* oComb = (bf16*)alloc((long)TOK * 2048 * 2);
    // scan machinery
    bf16* KLhi  = (bf16*)alloc((long)TOK * 512 * 2);
    bf16* KLlo  = (bf16*)alloc((long)TOK * 512 * 2);
    bf16* QLhi  = (bf16*)alloc((long)TOK * 2048 * 2);
    bf16* QLlo  = (bf16*)alloc((long)TOK * 2048 * 2);
    bf16* KThi  = (bf16*)alloc(1048576L * 2);
    bf16* KTlo  = (bf16*)alloc(1048576L * 2);
    bf16* Abhi  = (bf16*)alloc(128L * 4096 * 2);
    bf16* Ablo  = (bf16*)alloc(128L * 4096 * 2);
    float* ATf  = (float*)alloc(128L * 4096 * 4);
    bf16* Aqhi  = (bf16*)alloc(512L * 4096 * 2);
    bf16* Aqlo  = (bf16*)alloc(512L * 4096 * 2);
    bf16* S0Thi = (bf16*)alloc(513L * 16384 * 2);
    bf16* S0Tlo = (bf16*)alloc(513L * 16384 * 2);
    bf16* uTghi = (bf16*)alloc(512L * 128 * 64 * 2);
    bf16* uTglo = (bf16*)alloc(512L * 128 * 64 * 2);

    const int T256 = 256;
    // casts / transposes
    cast_split_k<<<(TOK * 2048 + 255) / 256, T256, 0, stream>>>(hs, hsHi, hsLo, (long)TOK * 2048);
    transpose_split_k<<<(2048L * 2048 + 255) / 256, T256, 0, stream>>>(Wq, WqTHi, WqTLo, 2048, 2048);
    transpose_split_k<<<(2048L * 512 + 255) / 256, T256, 0, stream>>>(Wk, WkTHi, WkTLo, 2048, 512);
    transpose_split_k<<<(2048L * 512 + 255) / 256, T256, 0, stream>>>(Wv, WvTHi, WvTLo, 2048, 512);
    transpose_split_k<<<(2048L * 2048 + 255) / 256, T256, 0, stream>>>(Wo, WoTHi, WoTLo, 2048, 2048);

    // projections (split-bf16 ~ fp32 accuracy), 64x64/wave register blocking
    gemm64_bt<true, false><<<dim3(256, 1, 1), T256, 0, stream>>>(
        hsHi, hsLo, WqTHi, WqTLo, qf, nullptr,
        2048, 2048, 2048, 2048, 2048, 2048, 0, 0, 0, 0, 0, 0, 1, 0, 0);
    gemm64_bt<true, false><<<dim3(64, 1, 1), T256, 0, stream>>>(
        hsHi, hsLo, WkTHi, WkTLo, kf, nullptr,
        2048, 512, 2048, 2048, 2048, 512, 0, 0, 0, 0, 0, 0, 1, 0, 0);
    gemm64_bt<true, false><<<dim3(64, 1, 1), T256, 0, stream>>>(
        hsHi, hsLo, WvTHi, WvTLo, vf, nullptr,
        2048, 512, 2048, 2048, 2048, 512, 0, 0, 0, 0, 0, 0, 1, 0, 0);

    // fused scan/attention input prep (R14): one pass over qf, one over kf
    softmaxq_fused_k<<<32768, 64, 0, stream>>>(qf, QLhi, QLlo, qhB);
    softmaxk_fused_k<<<8192, 64, 0, stream>>>(kf, KLb, KLhi, KLlo, khB, GLb);
    // merged vtrans + ktrans + vbpack
    prep_pack_k<<<(1048576 + 255) / 256, T256, 0, stream>>>(vf, KLb, GLb,
                                                            vT, KThi, KTlo, Vp, Bp);
    prepA_mfma_k<<<128, T256, 0, stream>>>(KLhi, KLlo, Abhi, Ablo, ATf);
    prepAq_mfma_k<<<512, T256, 0, stream>>>(QLhi, QLlo, KLhi, KLlo, Aqhi, Aqlo);

    // attention branch, chunked over 8 (b,h) pairs to bound the P buffer
    for (int z0 = 0; z0 < 32; z0 += 8) {
        gemm64_bt<false, true><<<dim3(64, 1, 8), T256, 0, stream>>>(
            qhB, nullptr, khB, nullptr, nullptr, P,
            1024, 1024, 128, 2048, 512, 1024,
            2097152L, 128L, 0L, 524288L, 128L, 1048576L, 16, 2, z0);
        softmax_causal_k<<<8192, 64, 0, stream>>>(P);
        gemm64_bt<false, true><<<dim3(8, 1, 8), T256, 0, stream>>>(
            P, nullptr, vT, nullptr, nullptr, oBase + (long)z0 * 131072,
            1024, 128, 1024, 1024, 1024, 128,
            0L, 0L, 1048576L, 524288L, 131072L, 131072L, 16, 2, z0);
    }

    // chunked delta-rule scan: sequential chain + parallel output pass
    seq_scan_k<<<8, 64, 0, stream>>>(KLhi, KLlo, KThi, KTlo, Abhi, Ablo, ATf, Vp, Bp,
                                     S0Thi, S0Tlo, uTghi, uTglo);
    pass2_o_k<<<4096, T256, 0, stream>>>(QLhi, QLlo, S0Thi, S0Tlo, Aqhi, Aqlo,
                                         uTghi, uTglo, oLin);

    // combine branches and output projection
    combine_k<<<(TOK * 2048 + 255) / 256, T256, 0, stream>>>(oLin, oBase, oComb, (long)TOK * 2048);
    gemm64_bt<false, false><<<dim3(256, 1, 1), T256, 0, stream>>>(
        oComb, nullptr, WoTHi, nullptr, (float*)d_out, nullptr,
        2048, 2048, 2048, 2048, 2048, 2048, 0, 0, 0, 0, 0, 0, 1, 0, 0);
}

// Round 16
// 4764.579 us; speedup vs baseline: 1.0321x; 1.0321x over previous
//
#include <hip/hip_runtime.h>
#include <hip/hip_bf16.h>
#include <hip/hip_fp16.h>
#include <math.h>

// Problem constants
#define BB 2
#define NN 1024
#define HID 2048
#define NH 16
#define KVH 4
#define DD 128
#define L_TOTAL 32768   // B*H*N flattened scan length
#define TOK 2048        // B*N tokens
#define NCHUNK 512      // 64-token chunks over the flattened sequence

typedef __bf16 bf16;
typedef __bf16 bf16x8 __attribute__((ext_vector_type(8)));
typedef __bf16 bf16x4 __attribute__((ext_vector_type(4)));
typedef __bf16 bf16x2 __attribute__((ext_vector_type(2)));
typedef float f32x4 __attribute__((ext_vector_type(4)));

// ---------------------------------------------------------------------------
// Register-blocked MFMA GEMM (R13): C[m,n] = sum_k A[m,k] * BT[n,k].
// 64x64 per wave (4x4 fragments), 128x128 per block. Per-output arithmetic
// bit-identical to the R1-verified gemm_bt.
// Grid.x = (M/128)*(N/128). Requires M%128==0, N%128==0, K%32==0.
// ---------------------------------------------------------------------------
template<bool SPLIT, bool OUTBF>
__global__ __launch_bounds__(256)
void gemm64_bt(const bf16* __restrict__ A, const bf16* __restrict__ Alo,
               const bf16* __restrict__ B, const bf16* __restrict__ Blo,
               float* __restrict__ Cf, bf16* __restrict__ Cb,
               int M, int N, int K, int lda, int ldb, int ldc,
               long aSb, long aSh, long aSz, long bSb, long bSh, long cSz,
               int zH, int gShift, int z0)
{
    const int zc   = blockIdx.z;
    const int z    = zc + z0;
    const int b    = z / zH;
    const int h    = z % zH;
    const int lane = threadIdx.x & 63;
    const int wave = threadIdx.x >> 6;
    const int tiles_n = N >> 7;
    const int btm = blockIdx.x / tiles_n;
    const int btn = blockIdx.x % tiles_n;
    const int wr = wave >> 1, wc = wave & 1;
    const int r0 = btm * 128 + wr * 64;
    const int c0 = btn * 128 + wc * 64;
    const int l15 = lane & 15, kq = lane >> 4;

    const long aoff = (long)b * aSb + (long)h * aSh + (long)zc * aSz;
    const long boff = (long)b * bSb + (long)(h >> gShift) * bSh;

    const bf16* ap[4];
    const bf16* bp[4];
    #pragma unroll
    for (int m = 0; m < 4; ++m)
        ap[m] = A + aoff + (long)(r0 + m * 16 + l15) * lda + kq * 8;
    #pragma unroll
    for (int n = 0; n < 4; ++n)
        bp[n] = B + boff + (long)(c0 + n * 16 + l15) * ldb + kq * 8;

    f32x4 acc[4][4];
    #pragma unroll
    for (int m = 0; m < 4; ++m)
        #pragma unroll
        for (int n = 0; n < 4; ++n)
            acc[m][n] = (f32x4){0.f, 0.f, 0.f, 0.f};

    for (int k0 = 0; k0 < K; k0 += 32) {
        bf16x8 ah[4], bh[4], al[4], bl[4];
        #pragma unroll
        for (int m = 0; m < 4; ++m) {
            ah[m] = *(const bf16x8*)ap[m];
            if (SPLIT) al[m] = *(const bf16x8*)(Alo + (ap[m] - A));
        }
        #pragma unroll
        for (int n = 0; n < 4; ++n) {
            bh[n] = *(const bf16x8*)bp[n];
            if (SPLIT) bl[n] = *(const bf16x8*)(Blo + (bp[n] - B));
        }
        #pragma unroll
        for (int m = 0; m < 4; ++m)
            #pragma unroll
            for (int n = 0; n < 4; ++n) {
                acc[m][n] = __builtin_amdgcn_mfma_f32_16x16x32_bf16(ah[m], bh[n], acc[m][n], 0, 0, 0);
                if (SPLIT) {
                    acc[m][n] = __builtin_amdgcn_mfma_f32_16x16x32_bf16(al[m], bh[n], acc[m][n], 0, 0, 0);
                    acc[m][n] = __builtin_amdgcn_mfma_f32_16x16x32_bf16(ah[m], bl[n], acc[m][n], 0, 0, 0);
                }
            }
        #pragma unroll
        for (int m = 0; m < 4; ++m) ap[m] += 32;
        #pragma unroll
        for (int n = 0; n < 4; ++n) bp[n] += 32;
    }

    // epilogue: C/D mapping as gemm_bt (col = lane&15, row = kq*4 + r)
    #pragma unroll
    for (int m = 0; m < 4; ++m)
        #pragma unroll
        for (int n = 0; n < 4; ++n) {
            const long cbase = (long)zc * cSz + (long)(c0 + n * 16 + l15);
            const int  rr0   = r0 + m * 16 + kq * 4;
            #pragma unroll
            for (int r = 0; r < 4; ++r) {
                long idx = cbase + (long)(rr0 + r) * ldc;
                if (OUTBF) Cb[idx] = (bf16)acc[m][n][r];
                else       Cf[idx] = acc[m][n][r];
            }
        }
}

// ---------------------------------------------------------------------------
// Elementwise helpers
// ---------------------------------------------------------------------------
__global__ void cast_split_k(const float* __restrict__ in, bf16* __restrict__ hi,
                             bf16* __restrict__ lo, long n)
{
    long i = (long)blockIdx.x * blockDim.x + threadIdx.x;
    if (i < n) {
        float x = in[i];
        bf16 h = (bf16)x;
        hi[i] = h;
        lo[i] = (bf16)(x - (float)h);
    }
}

__global__ void transpose_split_k(const float* __restrict__ in, bf16* __restrict__ hi,
                                  bf16* __restrict__ lo, int K, int N)
{
    long i = (long)blockIdx.x * blockDim.x + threadIdx.x;
    if (i < (long)K * N) {
        int n = (int)(i / K);
        int k = (int)(i % K);
        float x = in[(long)k * N + n];
        bf16 h = (bf16)x;
        hi[i] = h;
        lo[i] = (bf16)(x - (float)h);
    }
}

// R16-safe: merged vtrans + ktrans + vbpack (identical index domain, one
// launch). Per-output math identical to the three original kernels.
__global__ void prep_pack_k(const float* __restrict__ vf, const float* __restrict__ KLb,
                            const float* __restrict__ GLb,
                            bf16* __restrict__ vT, bf16* __restrict__ KThi,
                            bf16* __restrict__ KTlo, float* __restrict__ Vp,
                            float* __restrict__ Bp)
{
    long i = (long)blockIdx.x * blockDim.x + threadIdx.x;
    if (i < 1048576) {
        // vtrans: vT[b][kvh][m][d] = vf[(b*1024+m)*512 + kvh*128 + d]
        {
            int m   = (int)(i & 1023);
            int d   = (int)((i >> 10) & 127);
            int kvh = (int)((i >> 17) & 3);
            int b   = (int)(i >> 19);
            vT[i] = (bf16)vf[((long)(b * 1024 + m)) * 512 + kvh * 128 + d];
        }
        // ktrans: KT[a][d][t] = split(KLb[(b*1024+nc*64+t)*512 + kvh*128 + d])
        {
            int t = (int)(i & 63);
            int d = (int)((i >> 6) & 127);
            int a = (int)(i >> 13);
            int b = a >> 6, kvh = (a >> 4) & 3, nc = a & 15;
            float x = KLb[((long)(b * 1024 + nc * 64 + t)) * 512 + kvh * 128 + d];
            bf16 h = (bf16)x;
            KThi[i] = h;
            KTlo[i] = (bf16)(x - (float)h);
        }
        // vbpack: Vp/Bp[a][j][s]
        {
            int s = (int)(i & 63);
            int j = (int)((i >> 6) & 127);
            int a = (int)(i >> 13);
            int b = a >> 6, kvh = (a >> 4) & 3, nc = a & 15;
            long src = ((long)(b * 1024 + nc * 64 + s)) * 512 + kvh * 128 + j;
            Vp[i] = vf[src];
            Bp[i] = GLb[src];
        }
    }
}

// R14 fused q-prep: one read of the qf row produces (a) bf16 raw cast for the
// attention branch and (b) the hi/lo split of softmax(qf) for the scan.
__global__ void softmaxq_fused_k(const float* __restrict__ in,
                                 bf16* __restrict__ hi, bf16* __restrict__ lo,
                                 bf16* __restrict__ rawb)
{
    const int row  = blockIdx.x;
    const int lane = threadIdx.x;
    float2 v = ((const float2*)(in + (long)row * 128))[lane];
    ((bf16x2*)(rawb + (long)row * 128))[lane] = (bf16x2){(bf16)v.x, (bf16)v.y};
    float m = fmaxf(v.x, v.y);
    #pragma unroll
    for (int s = 1; s < 64; s <<= 1) m = fmaxf(m, __shfl_xor(m, s, 64));
    float ex = expf(v.x - m), ey = expf(v.y - m);
    float sum = ex + ey;
    #pragma unroll
    for (int s = 1; s < 64; s <<= 1) sum += __shfl_xor(sum, s, 64);
    float inv = 1.0f / sum;
    float x0 = ex * inv, x1 = ey * inv;
    bf16 h0 = (bf16)x0, h1 = (bf16)x1;
    ((bf16x2*)(hi + (long)row * 128))[lane] = (bf16x2){h0, h1};
    ((bf16x2*)(lo + (long)row * 128))[lane] =
        (bf16x2){(bf16)(x0 - (float)h0), (bf16)(x1 - (float)h1)};
}

// R14 fused k-prep: raw bf16 cast, logsig gate, f32 softmax, and hi/lo split.
__global__ void softmaxk_fused_k(const float* __restrict__ in,
                                 float* __restrict__ KLb,
                                 bf16* __restrict__ hi, bf16* __restrict__ lo,
                                 bf16* __restrict__ rawb, float* __restrict__ GLb)
{
    const int row  = blockIdx.x;
    const int lane = threadIdx.x;
    float2 v = ((const float2*)(in + (long)row * 128))[lane];
    ((bf16x2*)(rawb + (long)row * 128))[lane] = (bf16x2){(bf16)v.x, (bf16)v.y};
    float g0 = (fminf(v.x, 0.f) - log1pf(expf(-fabsf(v.x)))) * 0.0625f;
    float g1 = (fminf(v.y, 0.f) - log1pf(expf(-fabsf(v.y)))) * 0.0625f;
    ((float2*)(GLb + (long)row * 128))[lane] = make_float2(g0, g1);
    float m = fmaxf(v.x, v.y);
    #pragma unroll
    for (int s = 1; s < 64; s <<= 1) m = fmaxf(m, __shfl_xor(m, s, 64));
    float ex = expf(v.x - m), ey = expf(v.y - m);
    float sum = ex + ey;
    #pragma unroll
    for (int s = 1; s < 64; s <<= 1) sum += __shfl_xor(sum, s, 64);
    float inv = 1.0f / sum;
    float x0 = ex * inv, x1 = ey * inv;
    ((float2*)(KLb + (long)row * 128))[lane] = make_float2(x0, x1);
    bf16 h0 = (bf16)x0, h1 = (bf16)x1;
    ((bf16x2*)(hi + (long)row * 128))[lane] = (bf16x2){h0, h1};
    ((bf16x2*)(lo + (long)row * 128))[lane] =
        (bf16x2){(bf16)(x0 - (float)h0), (bf16)(x1 - (float)h1)};
}

__global__ void softmax_causal_k(bf16* __restrict__ P)
{
    const int row  = blockIdx.x;
    const int qi   = row & 1023;
    const int lane = threadIdx.x;
    bf16* p = P + (long)row * 1024;
    const float scale = 0.08838834764831845f;  // 1/sqrt(128)
    float vals[16];
    float m = -3.0e38f;
    #pragma unroll
    for (int t = 0; t < 16; ++t) {
        int j = lane + t * 64;
        float x = (j <= qi) ? (float)p[j] * scale : -3.0e38f;
        vals[t] = x;
        m = fmaxf(m, x);
    }
    #pragma unroll
    for (int s = 1; s < 64; s <<= 1) m = fmaxf(m, __shfl_xor(m, s, 64));
    float sum = 0.f;
    #pragma unroll
    for (int t = 0; t < 16; ++t) {
        float e = (vals[t] > -1.0e38f) ? expf(vals[t] - m) : 0.f;
        vals[t] = e;
        sum += e;
    }
    #pragma unroll
    for (int s = 1; s < 64; s <<= 1) sum += __shfl_xor(sum, s, 64);
    float inv = 1.f / sum;
    #pragma unroll
    for (int t = 0; t < 16; ++t) {
        int j = lane + t * 64;
        p[j] = (bf16)(vals[t] * inv);
    }
}

// A = tril_strict(K Kt) per kv-chunk (128) — MFMA version (R12).
__global__ __launch_bounds__(256)
void prepA_mfma_k(const bf16* __restrict__ KLhi, const bf16* __restrict__ KLlo,
                  bf16* __restrict__ Abhi, bf16* __restrict__ Ablo,
                  float* __restrict__ ATf)
{
    const int a = blockIdx.x;
    const int b = a >> 6, kvh = (a >> 4) & 3, nc = a & 15;
    const long rbase = ((long)(b * 1024 + nc * 64)) * 512 + kvh * 128;
    const int wave = threadIdx.x >> 6, lane = threadIdx.x & 63;
    const int l15 = lane & 15, kq = lane >> 4;

    #pragma unroll
    for (int it = 0; it < 4; ++it) {
        const int tile = wave * 4 + it;
        const int mt = tile >> 2, nt = tile & 3;    // mt: t-tile (rows), nt: s-tile (cols)
        f32x4 acc = {0.f, 0.f, 0.f, 0.f};
        if (nt <= mt) {                              // tiles above diagonal are all-zero
            const long arow = rbase + (long)(mt * 16 + l15) * 512 + kq * 8;
            const long brow = rbase + (long)(nt * 16 + l15) * 512 + kq * 8;
            #pragma unroll
            for (int ki = 0; ki < 4; ++ki) {
                bf16x8 ah = *(const bf16x8*)(KLhi + arow + ki * 32);
                bf16x8 al = *(const bf16x8*)(KLlo + arow + ki * 32);
                bf16x8 bh = *(const bf16x8*)(KLhi + brow + ki * 32);
                bf16x8 bl = *(const bf16x8*)(KLlo + brow + ki * 32);
                acc = __builtin_amdgcn_mfma_f32_16x16x32_bf16(ah, bh, acc, 0, 0, 0);
                acc = __builtin_amdgcn_mfma_f32_16x16x32_bf16(al, bh, acc, 0, 0, 0);
                acc = __builtin_amdgcn_mfma_f32_16x16x32_bf16(ah, bl, acc, 0, 0, 0);
            }
        }
        const int s  = nt * 16 + l15;                // C/D col = lane&15
        const int r0 = mt * 16 + kq * 4;             // C/D row = kq*4 + r
        #pragma unroll
        for (int r = 0; r < 4; ++r) {
            int t = r0 + r;
            float dot = (s < t) ? acc[r] : 0.f;
            bf16 hh = (bf16)dot;
            Abhi[(long)a * 4096 + t * 64 + s] = hh;
            Ablo[(long)a * 4096 + t * 64 + s] = (bf16)(dot - (float)hh);
            ATf[(long)a * 4096 + s * 64 + t] = dot;
        }
    }
}

// Aq = tril_inclusive(Q Kt) per chunk (512) — MFMA version (R12).
__global__ __launch_bounds__(256)
void prepAq_mfma_k(const bf16* __restrict__ QLhi, const bf16* __restrict__ QLlo,
                   const bf16* __restrict__ KLhi, const bf16* __restrict__ KLlo,
                   bf16* __restrict__ Aqhi, bf16* __restrict__ Aqlo)
{
    const int c = blockIdx.x;
    const int b = c >> 8, h = (c >> 4) & 15, nc = c & 15, kvh = h >> 2;
    const long qb = ((long)(b * 1024 + nc * 64)) * 2048 + h * 128;
    const long kb = ((long)(b * 1024 + nc * 64)) * 512 + kvh * 128;
    const int wave = threadIdx.x >> 6, lane = threadIdx.x & 63;
    const int l15 = lane & 15, kq = lane >> 4;

    #pragma unroll
    for (int it = 0; it < 4; ++it) {
        const int tile = wave * 4 + it;
        const int mt = tile >> 2, nt = tile & 3;
        f32x4 acc = {0.f, 0.f, 0.f, 0.f};
        if (nt <= mt) {                              // strict-upper tiles all-zero
            const long arow = qb + (long)(mt * 16 + l15) * 2048 + kq * 8;
            const long brow = kb + (long)(nt * 16 + l15) * 512 + kq * 8;
            #pragma unroll
            for (int ki = 0; ki < 4; ++ki) {
                bf16x8 ah = *(const bf16x8*)(QLhi + arow + ki * 32);
                bf16x8 al = *(const bf16x8*)(QLlo + arow + ki * 32);
                bf16x8 bh = *(const bf16x8*)(KLhi + brow + ki * 32);
                bf16x8 bl = *(const bf16x8*)(KLlo + brow + ki * 32);
                acc = __builtin_amdgcn_mfma_f32_16x16x32_bf16(ah, bh, acc, 0, 0, 0);
                acc = __builtin_amdgcn_mfma_f32_16x16x32_bf16(al, bh, acc, 0, 0, 0);
                acc = __builtin_amdgcn_mfma_f32_16x16x32_bf16(ah, bl, acc, 0, 0, 0);
            }
        }
        const int s  = nt * 16 + l15;
        const int r0 = mt * 16 + kq * 4;
        #pragma unroll
        for (int r = 0; r < 4; ++r) {
            int t = r0 + r;
            float dot = (s <= t) ? acc[r] : 0.f;
            bf16 hh = (bf16)dot;
            Aqhi[(long)c * 4096 + t * 64 + s] = hh;
            Aqlo[(long)c * 4096 + t * 64 + s] = (bf16)(dot - (float)hh);
        }
    }
}

// ---------------------------------------------------------------------------
// Sequential chunked delta-rule scan (R15 structure: ring depth 8, packed V/B).
// ---------------------------------------------------------------------------
__global__ __launch_bounds__(64, 1)
void seq_scan_k(const bf16* __restrict__ KLhi, const bf16* __restrict__ KLlo,
                const bf16* __restrict__ KThi, const bf16* __restrict__ KTlo,
                const bf16* __restrict__ Abhi, const bf16* __restrict__ Ablo,
                const float* __restrict__ ATf, const float* __restrict__ Vp,
                const float* __restrict__ Bp,
                bf16* __restrict__ S0Thi, bf16* __restrict__ S0Tlo,
                bf16* __restrict__ uTghi, bf16* __restrict__ uTglo)
{
    __shared__ __align__(16) bf16  SThi[16 * 128];
    __shared__ __align__(16) bf16  STlo[16 * 128];
    __shared__ __align__(16) bf16  uThi[16 * 64];
    __shared__ __align__(16) bf16  uTlo[16 * 64];
    __shared__ __align__(16) float xb[64 * 16];
    __shared__ __align__(16) float ATl[4096];

    const int lane  = threadIdx.x;
    const int jloc  = lane & 15;
    const int kq    = lane >> 4;          // quad 0..3
    const int jglob = blockIdx.x * 16 + jloc;

    // zero LDS state; zero S0T[0] slice for this block's columns
    for (int i = lane; i < 16 * 128; i += 64) { SThi[i] = (bf16)0.f; STlo[i] = (bf16)0.f; }
    for (int i = lane; i < 16 * 128; i += 64) {
        int j = i >> 7, d = i & 127;
        long off = (long)(blockIdx.x * 16 + j) * 128 + d;
        S0Thi[off] = (bf16)0.f;
        S0Tlo[off] = (bf16)0.f;
    }

    f32x4 S[8];
    #pragma unroll
    for (int m = 0; m < 8; ++m) S[m] = (f32x4){0.f, 0.f, 0.f, 0.f};

    for (int c = 0; c < NCHUNK; ++c) {
        const int b = c >> 8, h = (c >> 4) & 15, nc = c & 15;
        const int kvh = h >> 2, n0 = nc * 64;
        const long krow0  = ((long)(b * 1024 + n0)) * 512 + kvh * 128;   // KL rows, stride 512
        const int  achunk = (b * 4 + kvh) * 16 + nc;
        const long abase  = (long)achunk * 4096;
        const long ktbase = (long)achunk * 8192;                         // KT [d][t]
        const float* vpb  = Vp + ((long)achunk * 128 + jglob) * 64;
        const float* bpb  = Bp + ((long)achunk * 128 + jglob) * 64;

        // ---- KL fragments for this chunk (issued first: W consumes first)
        bf16x8 klh[16], kll[16];
        #pragma unroll
        for (int m = 0; m < 4; ++m)
            #pragma unroll
            for (int ki = 0; ki < 4; ++ki) {
                long ko = krow0 + (long)(m * 16 + jloc) * 512 + ki * 32 + kq * 8;
                klh[m * 4 + ki] = *(const bf16x8*)(KLhi + ko);
                kll[m * 4 + ki] = *(const bf16x8*)(KLlo + ko);
            }

        // ---- issue AT panel loads (regs); latency hides under W ----
        float4 atReg[16];
        {
            const float* src = ATf + abase;
            #pragma unroll
            for (int u = 0; u < 16; ++u)
                atReg[u] = *(const float4*)(src + u * 256 + lane * 4);
        }

        // ---- Ab correction fragments hoisted to chunk top (read-only) ----
        bf16x8 abh[4], abl[4];
        #pragma unroll
        for (int q = 0; q < 4; ++q) {
            const int tt = (q < 2) ? (16 + q * 16) : 48;   // 16,32,48,48
            const int kk = (q == 3) ? 1 : 0;
            long ao = abase + (long)(tt + jloc) * 64 + kk * 32 + kq * 8;
            abh[q] = *(const bf16x8*)(Abhi + ao);
            abl[q] = *(const bf16x8*)(Ablo + ao);
        }

        // ---- V/B for SB0 issued at chunk top (packed, float4) ----
        float Vv[2][16], Bv[2][16];
        #pragma unroll
        for (int g = 0; g < 4; ++g) {
            float4 v4 = *(const float4*)(vpb + g * 4);
            Vv[0][g * 4 + 0] = v4.x; Vv[0][g * 4 + 1] = v4.y;
            Vv[0][g * 4 + 2] = v4.z; Vv[0][g * 4 + 3] = v4.w;
            float4 b4 = *(const float4*)(bpb + g * 4);
            Bv[0][g * 4 + 0] = b4.x; Bv[0][g * 4 + 1] = b4.y;
            Bv[0][g * 4 + 2] = b4.z; Bv[0][g * 4 + 3] = b4.w;
        }

        // ---- W = K * S0 (3-MFMA split), KL from chunk-top registers ----
        f32x4 W[4];
        #pragma unroll
        for (int m = 0; m < 4; ++m) W[m] = (f32x4){0.f, 0.f, 0.f, 0.f};
        #pragma unroll
        for (int ki = 0; ki < 4; ++ki) {
            bf16x8 sh = *(const bf16x8*)&SThi[jloc * 128 + ki * 32 + kq * 8];
            bf16x8 sl = *(const bf16x8*)&STlo[jloc * 128 + ki * 32 + kq * 8];
            #pragma unroll
            for (int m = 0; m < 4; ++m) {
                W[m] = __builtin_amdgcn_mfma_f32_16x16x32_bf16(klh[m * 4 + ki], sh, W[m], 0, 0, 0);
                W[m] = __builtin_amdgcn_mfma_f32_16x16x32_bf16(kll[m * 4 + ki], sh, W[m], 0, 0, 0);
                W[m] = __builtin_amdgcn_mfma_f32_16x16x32_bf16(klh[m * 4 + ki], sl, W[m], 0, 0, 0);
            }
        }
        // epilogue: x[t][j] = W   (C/D: col=lane&15=j, row=kq*4+r)
        #pragma unroll
        for (int m = 0; m < 4; ++m)
            #pragma unroll
            for (int r = 0; r < 4; ++r)
                xb[(m * 16 + kq * 4 + r) * 16 + jloc] = W[m][r];

        // ---- commit AT panel to LDS (loads have retired by W's end) ----
        #pragma unroll
        for (int u = 0; u < 16; ++u)
            *(float4*)(ATl + u * 256 + lane * 4) = atReg[u];

        // ---- KT fragments issued here; latency hides under the SB loop ----
        bf16x8 kth[16], ktl[16];
        #pragma unroll
        for (int m = 0; m < 8; ++m)
            #pragma unroll
            for (int ki = 0; ki < 2; ++ki) {
                long o = ktbase + (long)(m * 16 + jloc) * 64 + ki * 32 + kq * 8;
                kth[m * 2 + ki] = *(const bf16x8*)(KThi + o);
                ktl[m * 2 + ki] = *(const bf16x8*)(KTlo + o);
            }

        // zero u buffers (cols 0..15 rewritten in SB0 before any read)
        {
            uint4 z = {0u, 0u, 0u, 0u};
            ((uint4*)uThi)[lane] = z; ((uint4*)uThi)[lane + 64] = z;
            ((uint4*)uTlo)[lane] = z; ((uint4*)uTlo)[lane + 64] = z;
        }

        // ---- 4 sub-blocks of 16 ----
        #pragma unroll
        for (int i = 0; i < 4; ++i) {
            const int T0 = i * 16;
            if (i > 0) {
                // cross-SB correction: corr[j][t] = sum_{s<16i} u[j][s]*A[t][s]
                const int K32 = (i + 1) >> 1;   // 1,1,2
                const int fb  = i - 1;          // hoisted-frag base
                f32x4 corr = (f32x4){0.f, 0.f, 0.f, 0.f};
                #pragma unroll
                for (int ki = 0; ki < 2; ++ki) if (ki < K32) {
                    bf16x8 uh = *(const bf16x8*)&uThi[jloc * 64 + ki * 32 + kq * 8];
                    bf16x8 ul = *(const bf16x8*)&uTlo[jloc * 64 + ki * 32 + kq * 8];
                    corr = __builtin_amdgcn_mfma_f32_16x16x32_bf16(uh, abh[fb + ki], corr, 0, 0, 0);
                    corr = __builtin_amdgcn_mfma_f32_16x16x32_bf16(ul, abh[fb + ki], corr, 0, 0, 0);
                    corr = __builtin_amdgcn_mfma_f32_16x16x32_bf16(uh, abl[fb + ki], corr, 0, 0, 0);
                }
                // D[m=j][n=t]: col=lane&15 -> t=T0+jloc ; rows j = kq*4+r. RMW into x.
                #pragma unroll
                for (int r = 0; r < 4; ++r)
                    xb[(T0 + jloc) * 16 + kq * 4 + r] += corr[r];
            }

            // Xv preload: take the per-step ds_read off the serial chain
            float Xv[16];
            #pragma unroll
            for (int s = 0; s < 16; ++s) Xv[s] = xb[(T0 + s) * 16 + jloc];

            // V/B prefetch for the NEXT sub-block (packed, float4)
            if (i < 3) {
                #pragma unroll
                for (int g = 0; g < 4; ++g) {
                    float4 v4 = *(const float4*)(vpb + T0 + 16 + g * 4);
                    Vv[(i + 1) & 1][g * 4 + 0] = v4.x; Vv[(i + 1) & 1][g * 4 + 1] = v4.y;
                    Vv[(i + 1) & 1][g * 4 + 2] = v4.z; Vv[(i + 1) & 1][g * 4 + 3] = v4.w;
                    float4 b4 = *(const float4*)(bpb + T0 + 16 + g * 4);
                    Bv[(i + 1) & 1][g * 4 + 0] = b4.x; Bv[(i + 1) & 1][g * 4 + 1] = b4.y;
                    Bv[(i + 1) & 1][g * 4 + 2] = b4.z; Bv[(i + 1) & 1][g * 4 + 3] = b4.w;
                }
            }

            // AT row prefetch ring (depth 8) from LDS, rows pre-masked
            float rb[8][16];
            #pragma unroll
            for (int p = 0; p < 8; ++p) {
                const float* rp = ATl + (T0 + p) * 64 + T0;
                #pragma unroll
                for (int g = 0; g < 4; ++g) {
                    float4 v4 = *(const float4*)(rp + g * 4);
                    rb[p][g * 4 + 0] = v4.x; rb[p][g * 4 + 1] = v4.y;
                    rb[p][g * 4 + 2] = v4.z; rb[p][g * 4 + 3] = v4.w;
                }
            }

            float acc[16];
            #pragma unroll
            for (int t = 0; t < 16; ++t) acc[t] = 0.f;

            #pragma unroll
            for (int s = 0; s < 16; ++s) {
                float u = Bv[i & 1][s] * (Vv[i & 1][s] - Xv[s] - acc[s]);
                bf16 uh = (bf16)u;
                bf16 ul = (bf16)(u - (float)uh);
                if (lane < 16) {
                    uThi[jloc * 64 + T0 + s] = uh;
                    uTlo[jloc * 64 + T0 + s] = ul;
                }
                // acc[t] += AT[s][t]*u for t>s (pruned statically)
                #pragma unroll
                for (int t = 0; t < 16; ++t)
                    if (t > s) acc[t] += rb[s & 7][t] * u;
                // refill ring slot with row s+8 (clamped; unused slots harmless)
                {
                    int rr = T0 + s + 8; if (rr > 63) rr = 63;
                    const float* rp = ATl + rr * 64 + T0;
                    #pragma unroll
                    for (int g = 0; g < 4; ++g) {
                        float4 v4 = *(const float4*)(rp + g * 4);
                        rb[s & 7][g * 4 + 0] = v4.x; rb[s & 7][g * 4 + 1] = v4.y;
                        rb[s & 7][g * 4 + 2] = v4.z; rb[s & 7][g * 4 + 3] = v4.w;
                    }
                }
            }
        }

        // ---- S += Kt * u (3-term split) ----
        #pragma unroll
        for (int ki = 0; ki < 2; ++ki) {
            bf16x8 uh = *(const bf16x8*)&uThi[jloc * 64 + ki * 32 + kq * 8];
            bf16x8 ul = *(const bf16x8*)&uTlo[jloc * 64 + ki * 32 + kq * 8];
            #pragma unroll
            for (int m = 0; m < 8; ++m) {
                S[m] = __builtin_amdgcn_mfma_f32_16x16x32_bf16(kth[m * 2 + ki], uh, S[m], 0, 0, 0);
                S[m] = __builtin_amdgcn_mfma_f32_16x16x32_bf16(kth[m * 2 + ki], ul, S[m], 0, 0, 0);
                S[m] = __builtin_amdgcn_mfma_f32_16x16x32_bf16(ktl[m * 2 + ki], uh, S[m], 0, 0, 0);
            }
        }

        // ---- bulk u -> global (coalesced; [c][jglob][s] contiguous per block)
        {
            const uint4* uh4 = (const uint4*)uThi;
            const uint4* ul4 = (const uint4*)uTlo;
            uint4* gh = (uint4*)(uTghi + ((long)c * 128 + blockIdx.x * 16) * 64);
            uint4* gl = (uint4*)(uTglo + ((long)c * 128 + blockIdx.x * 16) * 64);
            gh[lane] = uh4[lane]; gh[lane + 64] = uh4[lane + 64];
            gl[lane] = ul4[lane]; gl[lane + 64] = ul4[lane + 64];
        }

        // ---- S split epilogue: ST (LDS, next chunk) + S0T[c+1] (global, pass 2)
        #pragma unroll
        for (int m = 0; m < 8; ++m) {
            bf16x4 h4, l4;
            #pragma unroll
            for (int r = 0; r < 4; ++r) {
                float v = S[m][r];
                bf16 hh = (bf16)v;
                h4[r] = hh;
                l4[r] = (bf16)(v - (float)hh);
            }
            int d0 = m * 16 + kq * 4;
            *(bf16x4*)&SThi[jloc * 128 + d0] = h4;
            *(bf16x4*)&STlo[jloc * 128 + d0] = l4;
            long goff = (long)(c + 1) * 16384 + (long)jglob * 128 + d0;
            *(bf16x4*)(S0Thi + goff) = h4;
            *(bf16x4*)(S0Tlo + goff) = l4;
        }
    }
}

// ---------------------------------------------------------------------------
// Pass 2 (fully parallel): o[t][j] = Q*S0_c + tril_incl(Aq)*u  per chunk.
// ---------------------------------------------------------------------------
__global__ __launch_bounds__(256)
void pass2_o_k(const bf16* __restrict__ QLhi, const bf16* __restrict__ QLlo,
               const bf16* __restrict__ S0Thi, const bf16* __restrict__ S0Tlo,
               const bf16* __restrict__ Aqhi, const bf16* __restrict__ Aqlo,
               const bf16* __restrict__ uTghi, const bf16* __restrict__ uTglo,
               float* __restrict__ O)
{
    const int c    = blockIdx.x >> 3;
    const int tg   = blockIdx.x & 7;
    const int wave = threadIdx.x >> 6;
    const int lane = threadIdx.x & 63;
    const int tt   = tg * 4 + wave;
    const int mt   = tt >> 3, nt = tt & 7;
    const int b = c >> 8, h = (c >> 4) & 15, nc = c & 15, n0 = nc * 64;
    const int kq = lane >> 4, l15 = lane & 15;

    const long qrow   = ((long)(b * 1024 + n0 + mt * 16 + l15)) * 2048 + h * 128;
    const long sbase  = (long)c * 16384 + (long)(nt * 16 + l15) * 128;
    const long aqbase = (long)c * 4096 + (long)(mt * 16 + l15) * 64;
    const long ubase  = ((long)(c * 128 + nt * 16 + l15)) * 64;

    f32x4 acc = {0.f, 0.f, 0.f, 0.f};
    #pragma unroll
    for (int ki = 0; ki < 4; ++ki) {
        bf16x8 qh = *(const bf16x8*)(QLhi + qrow + ki * 32 + kq * 8);
        bf16x8 ql = *(const bf16x8*)(QLlo + qrow + ki * 32 + kq * 8);
        bf16x8 sh = *(const bf16x8*)(S0Thi + sbase + ki * 32 + kq * 8);
        bf16x8 sl = *(const bf16x8*)(S0Tlo + sbase + ki * 32 + kq * 8);
        acc = __builtin_amdgcn_mfma_f32_16x16x32_bf16(qh, sh, acc, 0, 0, 0);
        acc = __builtin_amdgcn_mfma_f32_16x16x32_bf16(ql, sh, acc, 0, 0, 0);
        acc = __builtin_amdgcn_mfma_f32_16x16x32_bf16(qh, sl, acc, 0, 0, 0);
    }
    #pragma unroll
    for (int ki = 0; ki < 2; ++ki) {
        bf16x8 ah = *(const bf16x8*)(Aqhi + aqbase + ki * 32 + kq * 8);
        bf16x8 al = *(const bf16x8*)(Aqlo + aqbase + ki * 32 + kq * 8);
        bf16x8 uh = *(const bf16x8*)(uTghi + ubase + ki * 32 + kq * 8);
        bf16x8 ul = *(const bf16x8*)(uTglo + ubase + ki * 32 + kq * 8);
        acc = __builtin_amdgcn_mfma_f32_16x16x32_bf16(ah, uh, acc, 0, 0, 0);
        acc = __builtin_amdgcn_mfma_f32_16x16x32_bf16(al, uh, acc, 0, 0, 0);
        acc = __builtin_amdgcn_mfma_f32_16x16x32_bf16(ah, ul, acc, 0, 0, 0);
    }
    #pragma unroll
    for (int r = 0; r < 4; ++r)
        O[((long)c * 64 + mt * 16 + kq * 4 + r) * 128 + nt * 16 + l15] = acc[r];
}

// oComb[(b,n),(h,d)] = 0.5*(oLin[(b,h,n),d] + oBase[(b,h,n),d])  -> bf16
__global__ void combine_k(const float* __restrict__ oLin, const bf16* __restrict__ oBase,
                          bf16* __restrict__ oComb, long n)
{
    long i = (long)blockIdx.x * blockDim.x + threadIdx.x;
    if (i < n) {
        int d  = (int)(i & 127);
        int hh = (int)((i >> 7) & 15);
        int nn = (int)((i >> 11) & 1023);
        int b  = (int)(i >> 21);
        long src = ((long)((b * 16 + hh) * 1024 + nn)) * 128 + d;
        oComb[i] = (bf16)(0.5f * (oLin[src] + (float)oBase[src]));
    }
}

// ---------------------------------------------------------------------------
extern "C" void kernel_launch(void* const* d_in, const int* in_sizes, int n_in,
                              void* d_out, int out_size, void* d_ws, size_t ws_size,
                              hipStream_t stream)
{
    const float* hs = (const float*)d_in[0];
    const float* Wq = (const float*)d_in[1];
    const float* Wk = (const float*)d_in[2];
    const float* Wv = (const float*)d_in[3];
    const float* Wo = (const float*)d_in[4];

    char* base = (char*)d_ws;
    size_t off = 0;
    auto alloc = [&](size_t bytes) -> char* {
        char* r = base + off;
        off += (bytes + 255) & ~(size_t)255;
        return r;
    };

    bf16* hsHi  = (bf16*)alloc((long)TOK * 2048 * 2);
    bf16* hsLo  = (bf16*)alloc((long)TOK * 2048 * 2);
    bf16* WqTHi = (bf16*)alloc(2048L * 2048 * 2);
    bf16* WqTLo = (bf16*)alloc(2048L * 2048 * 2);
    bf16* WkTHi = (bf16*)alloc(512L * 2048 * 2);
    bf16* WkTLo = (bf16*)alloc(512L * 2048 * 2);
    bf16* WvTHi = (bf16*)alloc(512L * 2048 * 2);
    bf16* WvTLo = (bf16*)alloc(512L * 2048 * 2);
    bf16* WoTHi = (bf16*)alloc(2048L * 2048 * 2);
    bf16* WoTLo = (bf16*)alloc(2048L * 2048 * 2);
    float* qf   = (float*)alloc((long)TOK * 2048 * 4);
    float* kf   = (float*)alloc((long)TOK * 512 * 4);
    float* vf   = (float*)alloc((long)TOK * 512 * 4);
    float* KLb  = (float*)alloc((long)TOK * 512 * 4);
    float* GLb  = (float*)alloc((long)TOK * 512 * 4);
    float* Vp   = (float*)alloc(1048576L * 4);
    float* Bp   = (float*)alloc(1048576L * 4);
    bf16* qhB   = (bf16*)alloc((long)TOK * 2048 * 2);
    bf16* khB   = (bf16*)alloc((long)TOK * 512 * 2);
    bf16* vT    = (bf16*)alloc(1048576L * 2);
    bf16* P     = (bf16*)alloc(8L * 1024 * 1024 * 2);
    float* oLin = (float*)alloc(32768L * 128 * 4);
    bf16* oBase = (bf16*)alloc(32768L * 128 * 2);
    bf16* oComb = (bf16*)alloc((long)TOK * 2048 * 2);
    // scan machinery
    bf16* KLhi  = (bf16*)alloc((long)TOK * 512 * 2);
    bf16* KLlo  = (bf16*)alloc((long)TOK * 512 * 2);
    bf16* QLhi  = (bf16*)alloc((long)TOK * 2048 * 2);
    bf16* QLlo  = (bf16*)alloc((long)TOK * 2048 * 2);
    bf16* KThi  = (bf16*)alloc(1048576L * 2);
    bf16* KTlo  = (bf16*)alloc(1048576L * 2);
    bf16* Abhi  = (bf16*)alloc(128L * 4096 * 2);
    bf16* Ablo  = (bf16*)alloc(128L * 4096 * 2);
    float* ATf  = (float*)alloc(128L * 4096 * 4);
    bf16* Aqhi  = (bf16*)alloc(512L * 4096 * 2);
    bf16* Aqlo  = (bf16*)alloc(512L * 4096 * 2);
    bf16* S0Thi = (bf16*)alloc(513L * 16384 * 2);
    bf16* S0Tlo = (bf16*)alloc(513L * 16384 * 2);
    bf16* uTghi = (bf16*)alloc(512L * 128 * 64 * 2);
    bf16* uTglo = (bf16*)alloc(512L * 128 * 64 * 2);

    const int T256 = 256;
    // casts / transposes
    cast_split_k<<<(TOK * 2048 + 255) / 256, T256, 0, stream>>>(hs, hsHi, hsLo, (long)TOK * 2048);
    transpose_split_k<<<(2048L * 2048 + 255) / 256, T256, 0, stream>>>(Wq, WqTHi, WqTLo, 2048, 2048);
    transpose_split_k<<<(2048L * 512 + 255) / 256, T256, 0, stream>>>(Wk, WkTHi, WkTLo, 2048, 512);
    transpose_split_k<<<(2048L * 512 + 255) / 256, T256, 0, stream>>>(Wv, WvTHi, WvTLo, 2048, 512);
    transpose_split_k<<<(2048L * 2048 + 255) / 256, T256, 0, stream>>>(Wo, WoTHi, WoTLo, 2048, 2048);

    // projections (split-bf16 ~ fp32 accuracy), 64x64/wave register blocking
    gemm64_bt<true, false><<<dim3(256, 1, 1), T256, 0, stream>>>(
        hsHi, hsLo, WqTHi, WqTLo, qf, nullptr,
        2048, 2048, 2048, 2048, 2048, 2048, 0, 0, 0, 0, 0, 0, 1, 0, 0);
    gemm64_bt<true, false><<<dim3(64, 1, 1), T256, 0, stream>>>(
        hsHi, hsLo, WkTHi, WkTLo, kf, nullptr,
        2048, 512, 2048, 2048, 2048, 512, 0, 0, 0, 0, 0, 0, 1, 0, 0);
    gemm64_bt<true, false><<<dim3(64, 1, 1), T256, 0, stream>>>(
        hsHi, hsLo, WvTHi, WvTLo, vf, nullptr,
        2048, 512, 2048, 2048, 2048, 512, 0, 0, 0, 0, 0, 0, 1, 0, 0);

    // fused scan/attention input prep (R14): one pass over qf, one over kf
    softmaxq_fused_k<<<32768, 64, 0, stream>>>(qf, QLhi, QLlo, qhB);
    softmaxk_fused_k<<<8192, 64, 0, stream>>>(kf, KLb, KLhi, KLlo, khB, GLb);
    // merged vtrans + ktrans + vbpack
    prep_pack_k<<<(1048576 + 255) / 256, T256, 0, stream>>>(vf, KLb, GLb,
                                                            vT, KThi, KTlo, Vp, Bp);
    prepA_mfma_k<<<128, T256, 0, stream>>>(KLhi, KLlo, Abhi, Ablo, ATf);
    prepAq_mfma_k<<<512, T256, 0, stream>>>(QLhi, QLlo, KLhi, KLlo, Aqhi, Aqlo);

    // attention branch, chunked over 8 (b,h) pairs to bound the P buffer
    for (int z0 = 0; z0 < 32; z0 += 8) {
        gemm64_bt<false, true><<<dim3(64, 1, 8), T256, 0, stream>>>(
            qhB, nullptr, khB, nullptr, nullptr, P,
            1024, 1024, 128, 2048, 512, 1024,
            2097152L, 128L, 0L, 524288L, 128L, 1048576L, 16, 2, z0);
        softmax_causal_k<<<8192, 64, 0, stream>>>(P);
        gemm64_bt<false, true><<<dim3(8, 1, 8), T256, 0, stream>>>(
            P, nullptr, vT, nullptr, nullptr, oBase + (long)z0 * 131072,
            1024, 128, 1024, 1024, 1024, 128,
            0L, 0L, 1048576L, 524288L, 131072L, 131072L, 16, 2, z0);
    }

    // chunked delta-rule scan: sequential chain + parallel output pass
    seq_scan_k<<<8, 64, 0, stream>>>(KLhi, KLlo, KThi, KTlo, Abhi, Ablo, ATf, Vp, Bp,
                                     S0Thi, S0Tlo, uTghi, uTglo);
    pass2_o_k<<<4096, T256, 0, stream>>>(QLhi, QLlo, S0Thi, S0Tlo, Aqhi, Aqlo,
                                         uTghi, uTglo, oLin);

    // combine branches and output projection
    combine_k<<<(TOK * 2048 + 255) / 256, T256, 0, stream>>>(oLin, oBase, oComb, (long)TOK * 2048);
    gemm64_bt<false, false><<<dim3(256, 1, 1), T256, 0, stream>>>(
        oComb, nullptr, WoTHi, nullptr, (float*)d_out, nullptr,
        2048, 2048, 2048, 2048, 2048, 2048, 0, 0, 0, 0, 0, 0, 1, 0, 0);
}